// Round 9
// baseline (87.485 us; speedup 1.0000x reference)
//
#include <hip/hip_runtime.h>
#include <cstdint>
#include <cstddef>

#define W_ 512
#define H_ 512
#define N_ 8
#define C_ 19
#define HW_ (W_*H_)      // 262144 = 2^18
#define NPIX_ (N_*HW_)   // 2^21

#define TS  32           // output tile side
#define SR  46           // sml region rows (halo 7)
#define SC  48           // sml region cols: [tx0-8, tx0+40), 16B-aligned
#define BR  52           // bnd-mask rows per tile: [ty0-10, ty0+42)

typedef float   f32x4 __attribute__((ext_vector_type(4)));
typedef uint8_t u8x4  __attribute__((ext_vector_type(4)));
typedef unsigned long long u64;

// ---------------- K1: channel max/argmax -> sml, pred(u8), pred(float out) ----
// (unchanged from R8; launched TWICE this round for warm-vs-cold attribution)
__global__ __launch_bounds__(256) void k_argmax_sml(
    const float* __restrict__ x, const float* __restrict__ means,
    const float* __restrict__ stdv, float* __restrict__ sml,
    uint8_t* __restrict__ pred8, float* __restrict__ predf)
{
    __shared__ float ms[C_], rs[C_];
    const int tid = threadIdx.x;
    if (tid < C_) {
        ms[tid] = means[tid];
        rs[tid] = __builtin_amdgcn_rcpf(stdv[tid]);
    }

    const int seg = blockIdx.x * 4096;          // 4096 px per block
    const int n   = seg >> 18;
    const int p0  = seg & (HW_ - 1);
    const float* base = x + (size_t)n * C_ * HW_ + p0 + 4 * tid;

    f32x4 mv[4];
    int   idx[4][4];
    #pragma unroll
    for (int j = 0; j < 4; ++j) {
        mv[j] = *(const f32x4*)(base + j * 1024);
        idx[j][0] = idx[j][1] = idx[j][2] = idx[j][3] = 0;
    }
    for (int c = 1; c < C_; ++c) {
        const float* bc = base + (size_t)c * HW_;
        #pragma unroll
        for (int j = 0; j < 4; ++j) {
            f32x4 v = *(const f32x4*)(bc + j * 1024);
            #pragma unroll
            for (int k = 0; k < 4; ++k) {
                if (v[k] > mv[j][k]) { mv[j][k] = v[k]; idx[j][k] = c; }
            }
        }
    }
    __syncthreads();                             // ms/rs ready
    #pragma unroll
    for (int j = 0; j < 4; ++j) {
        int pix = seg + j * 1024 + 4 * tid;
        f32x4 s, pf; u8x4 pc;
        #pragma unroll
        for (int k = 0; k < 4; ++k) {
            s[k]  = (mv[j][k] - ms[idx[j][k]]) * rs[idx[j][k]];
            pf[k] = (float)idx[j][k];
            pc[k] = (uint8_t)idx[j][k];
        }
        *(f32x4*)(sml + pix) = s;
        *(u8x4*)(pred8 + pix) = pc;
        __builtin_nontemporal_store(pf, (f32x4*)(predf + pix));
    }
}

// ---------------- K2: boundary bits -> packed row masks (8 u64 per row) ------
__global__ __launch_bounds__(256) void k_bnd(
    const uint8_t* __restrict__ pred8, u64* __restrict__ bndM)
{
    int gid  = blockIdx.x * 256 + threadIdx.x;
    int lane = gid & 63;
    int wave = gid >> 6;
    int w = wave & 7;
    int y = (wave >> 3) & 511;
    int n = wave >> 12;
    int xx = w * 64 + lane;
    const uint8_t* pc = pred8 + (size_t)n * HW_ + y * W_ + xx;
    int c = pc[0];
    bool u = y > 0, d = y < H_-1, l = xx > 0, r = xx < W_-1;
    int up = u ? pc[-W_] : c;
    int dn = d ? pc[ W_] : c;
    int lf = l ? pc[-1]  : c;
    int rt = r ? pc[ 1]  : c;
    int mx = max(max(c, up), max(dn, max(lf, rt)));       // cross dilate
    int mn = min(min(c, up), min(dn, min(lf, rt)));       // full 3x3 erode
    int c00 = (u && l) ? pc[-W_-1] : c;
    int c01 = (u && r) ? pc[-W_+1] : c;
    int c10 = (d && l) ? pc[ W_-1] : c;
    int c11 = (d && r) ? pc[ W_+1] : c;
    mn = min(mn, min(min(c00, c01), min(c10, c11)));
    u64 m = __ballot(mx != mn);
    if (lane == 0) bndM[((size_t)n * 512 + y) * 8 + w] = m;
}

// ---------------- K3: fused masks + (skippable) smooth + separable conv ------
__global__ __launch_bounds__(256) void k_fused(
    const float* __restrict__ sml_g, const u64* __restrict__ bndM,
    const float* __restrict__ gk, float* __restrict__ out)
{
    __shared__ float smlA[SR*SC];
    __shared__ float smlB[SR*SC];           // active-staging; later aliased as htmp
    __shared__ u64 M0[BR], E1[BR], E2[BR], E3[BR], VM[BR];
    __shared__ u64 NBM[4][BR];
    __shared__ float g7[7];
    __shared__ int tACT;

    const int tid = threadIdx.x;
    const int bx = blockIdx.x, by = blockIdx.y, n = blockIdx.z;
    const int tx0 = bx * TS, ty0 = by * TS;
    const float* sg = sml_g + (size_t)n * HW_;

    if (tid == 0) tACT = 0;
    if (tid < 7) g7[tid] = gk[21 + tid] / sqrtf(gk[24]);   // kk = outer(g,g)

    // ---- load 52 bnd row-masks (window [tx0-10, tx0+42)) + validity masks ----
    if (tid < BR) {
        int gy = ty0 + tid - 10;
        int bx0 = tx0 - 10;
        u64 m = 0, vm = 0;
        if (gy >= 0 && gy < H_) {
            const u64* row = bndM + ((size_t)n * 512 + gy) * 8;
            int sft = bx0 & 63;
            int wi  = bx0 >> 6;                           // arithmetic: -10 -> -1
            u64 w0 = (wi >= 0) ? row[wi] : 0ULL;
            u64 w1 = (wi + 1 <= 7) ? row[wi + 1] : 0ULL;
            m = sft ? ((w0 >> sft) | (w1 << (64 - sft))) : w0;
            int lo = bx0 < 0 ? -bx0 : 0;
            int hi = (512 - bx0) < BR ? (512 - bx0) : BR;
            if (hi > lo) vm = ((1ULL << (hi - lo)) - 1ULL) << lo;
        }
        M0[tid] = m;
        VM[tid] = vm;
    }

    // ---- load sml region 46x48; OOB -> 0 (zero-pad for conv & masked sums) ----
    if (bx > 0 && bx < (W_/TS - 1)) {
        for (int s = tid; s < SR * (SC/4); s += 256) {
            int ly = s / (SC/4), j = s - ly * (SC/4);
            int gy = ty0 + ly - 7;
            f32x4 v = {0.f, 0.f, 0.f, 0.f};
            if ((unsigned)gy < (unsigned)H_)
                v = *(const f32x4*)(sg + (size_t)gy * W_ + (tx0 - 8) + j * 4);
            *(f32x4*)&smlA[ly * SC + j * 4] = v;
        }
    } else {
        for (int s = tid; s < SR * SC; s += 256) {
            int ly = s / SC, lx = s - ly * SC;
            int gy = ty0 + ly - 7, gx = tx0 + lx - 8;
            float v = 0.f;
            if ((unsigned)gy < (unsigned)H_ && (unsigned)gx < (unsigned)W_)
                v = sg[(size_t)gy * W_ + gx];
            smlA[ly * SC + lx] = v;
        }
    }
    __syncthreads();

    // ---- cross-dilations: E_{k+1}[y] = dx(E_k[y]) | E_k[y-1] | E_k[y+1] ----
    if (tid < BR) {
        u64 a = M0[tid], u = tid > 0 ? M0[tid-1] : 0, d = tid < BR-1 ? M0[tid+1] : 0;
        E1[tid] = a | (a << 1) | (a >> 1) | u | d;
    }
    __syncthreads();
    if (tid < BR) {
        u64 a = E1[tid], u = tid > 0 ? E1[tid-1] : 0, d = tid < BR-1 ? E1[tid+1] : 0;
        E2[tid] = a | (a << 1) | (a >> 1) | u | d;
    }
    __syncthreads();
    if (tid < BR) {
        u64 a = E2[tid], u = tid > 0 ? E2[tid-1] : 0, d = tid < BR-1 ? E2[tid+1] : 0;
        E3[tid] = a | (a << 1) | (a >> 1) | u | d;
    }
    __syncthreads();
    {   // NB_r = ~E_r & valid   (r = 0..3 across the 4 thread quarters)
        int r = tid >> 6, i = tid & 63;
        if (i < BR) {
            u64 e = (r == 0) ? M0[i] : (r == 1) ? E1[i] : (r == 2) ? E2[i] : E3[i];
            NBM[r][i] = ~e & VM[i];
        }
    }
    __syncthreads();

    // ---- active detection: px can change in some pass only if 3x3 window ∩ NB0 ≠ ∅
    u64 actRow = 0;
    if (tid < SR) {
        int bi = tid + 3;
        u64 U = NBM[0][bi-1] | NBM[0][bi] | NBM[0][bi+1];
        u64 A = (U >> 1) | (U >> 2) | (U >> 3);
        int lo = tx0 == 0 ? 8 : 0;
        int hi = tx0 == (W_-TS) ? 40 : SC;
        u64 CV = (hi - lo >= 64) ? ~0ULL : (((1ULL << (hi - lo)) - 1ULL) << lo);
        actRow = A & CV;
        int gy = ty0 + tid - 7;
        if ((unsigned)gy >= (unsigned)H_) actRow = 0;
        if (actRow) tACT = 1;                              // benign race (same value)
    }
    __syncthreads();

    // ---- 4 smoothing passes r=3,2,1,0 — executed only where actives exist ----
    if (tACT) {
        #pragma unroll
        for (int k = 0; k < 4; ++k) {
            const int r = 3 - k;
            const u64 colmask = ((1ULL << (44 - 2*k)) - 1ULL) << (2 + k);
            u64 mwork = 0;
            if (tid >= 1 + k && tid < 45 - k && tid < SR)
                mwork = actRow & colmask;
            u64 mm = mwork;
            while (mm) {
                int lx = __ffsll(mm) - 1; mm &= mm - 1;
                int bi = tid + 3, sh = lx + 1;
                u64 fu = (NBM[r][bi-1] >> sh) & 7ULL;
                u64 fc = (NBM[r][bi  ] >> sh) & 7ULL;
                u64 fd = (NBM[r][bi+1] >> sh) & 7ULL;
                float c = smlA[tid*SC + lx];
                float o;
                if (((fc >> 1) & 1ULL) || !(fu | fc | fd)) {
                    o = c;
                } else {
                    int cnt = __popcll(fu) + __popcll(fc) + __popcll(fd);
                    float sum = 0.f;
                    const float* r0 = &smlA[(tid-1)*SC + lx];
                    const float* r1 = &smlA[(tid  )*SC + lx];
                    const float* r2 = &smlA[(tid+1)*SC + lx];
                    if (fu & 1) sum += r0[-1];
                    if (fu & 2) sum += r0[0];
                    if (fu & 4) sum += r0[1];
                    if (fc & 1) sum += r1[-1];
                    if (fc & 4) sum += r1[1];
                    if (fd & 1) sum += r2[-1];
                    if (fd & 2) sum += r2[0];
                    if (fd & 4) sum += r2[1];
                    o = sum / (float)cnt;
                }
                smlB[tid*SC + lx] = o;
            }
            __syncthreads();
            mm = mwork;
            while (mm) {
                int lx = __ffsll(mm) - 1; mm &= mm - 1;
                smlA[tid*SC + lx] = smlB[tid*SC + lx];
            }
            __syncthreads();
        }
    }

    // ---- separable 7x7 gaussian: horizontal into smlB(htmp), then vertical ----
    float* htmp = smlB;
    for (int s = tid; s < 38 * 32; s += 256) {
        int hy = s >> 5, hx = s & 31;
        const float* p = &smlA[(hy + 4)*SC + (hx + 5)];
        htmp[hy*33 + hx] = g7[0]*p[0] + g7[1]*p[1] + g7[2]*p[2] + g7[3]*p[3]
                         + g7[4]*p[4] + g7[5]*p[5] + g7[6]*p[6];
    }
    __syncthreads();
    for (int s = tid; s < TS*TS; s += 256) {
        int oy = s >> 5, ox = s & 31;
        const float* p = &htmp[oy*33 + ox];
        float a = g7[0]*p[0]   + g7[1]*p[33]  + g7[2]*p[66]  + g7[3]*p[99]
                + g7[4]*p[132] + g7[5]*p[165] + g7[6]*p[198];
        out[(size_t)n*HW_ + (size_t)(ty0 + oy)*W_ + (tx0 + ox)] = a;
    }
}

extern "C" void kernel_launch(void* const* d_in, const int* in_sizes, int n_in,
                              void* d_out, int out_size, void* d_ws, size_t ws_size,
                              hipStream_t stream)
{
    const float* x     = (const float*)d_in[0];
    const float* means = (const float*)d_in[1];
    const float* stdv  = (const float*)d_in[2];
    const float* gk    = (const float*)d_in[3];
    float* out_sml  = (float*)d_out;
    float* out_pred = (float*)d_out + NPIX_;

    char* ws = (char*)d_ws;
    float*   sml   = (float*)(ws);                 // 8,388,608 B
    uint8_t* pred8 = (uint8_t*)(ws + 8388608);     // 2,097,152 B
    u64*     bndM  = (u64*)(ws + 10485760);        //   262,144 B

    // ATTRIBUTION ROUND: K1 launched TWICE (idempotent — rewrites identical
    // sml/pred8/predf). dur_R9 - dur_R8 = K1_warm (x L3-resident iff L3 retains).
    k_argmax_sml<<<NPIX_/16/256, 256, 0, stream>>>(x, means, stdv, sml, pred8, out_pred);
    k_argmax_sml<<<NPIX_/16/256, 256, 0, stream>>>(x, means, stdv, sml, pred8, out_pred);
    k_bnd<<<NPIX_/256, 256, 0, stream>>>(pred8, bndM);
    dim3 fgrd(W_/TS, H_/TS, N_);
    k_fused<<<fgrd, 256, 0, stream>>>(sml, bndM, gk, out_sml);
}

// Round 10
// 51.919 us; speedup vs baseline: 1.6850x; 1.6850x over previous
//
#include <hip/hip_runtime.h>
#include <cstdint>
#include <cstddef>

#define W_ 512
#define H_ 512
#define N_ 8
#define C_ 19
#define HW_ (W_*H_)      // 262144 = 2^18
#define NPIX_ (N_*HW_)   // 2^21

#define TS  32           // output tile side
#define SR  46           // sml region rows (halo 7)
#define SC  48           // sml region cols: [tx0-8, tx0+40), 16B-aligned
#define BR  52           // bnd-mask rows per tile: [ty0-10, ty0+42)

typedef float   f32x4 __attribute__((ext_vector_type(4)));
typedef uint8_t u8x4  __attribute__((ext_vector_type(4)));
typedef unsigned long long u64;

// ---------------- K1: channel max/argmax via global_load_lds DMA staging -----
// R10: stage 1024 px x 19 ch (76 KB) into LDS via async DMA (width=16),
// then argmax from LDS. Tests whether the LDS-DMA path sustains more
// outstanding misses than the VGPR-return load path (K1 stuck at ~3 TB/s
// across all previous structural variants).
__global__ __launch_bounds__(256) void k_argmax_sml(
    const float* __restrict__ x, const float* __restrict__ means,
    const float* __restrict__ stdv, float* __restrict__ sml,
    uint8_t* __restrict__ pred8, float* __restrict__ predf)
{
    __shared__ float xs[C_ * 1024];      // [c][1024 px chunk]  76,800 B
    __shared__ float ms[C_], rs[C_];
    const int tid = threadIdx.x;
    if (tid < C_) {
        ms[tid] = means[tid];
        rs[tid] = __builtin_amdgcn_rcpf(stdv[tid]);
    }

    const int chunk = blockIdx.x;            // 1024 px per block
    const int n   = chunk >> 8;              // HW_/1024 = 256 chunks/image
    const int p0  = (chunk & 255) << 10;
    const int wv  = tid >> 6, lane = tid & 63;
    const float* xg = x + (size_t)n * C_ * HW_ + p0;

    // wave wv stages channels [5*wv, 5*wv+5) (last wave: 4 channels);
    // per channel: 4 x 1KB DMA = 4KB contiguous burst (same shape as R8).
    int cLo = wv * 5;
    int cHi = cLo + 5 > C_ ? C_ : cLo + 5;
    for (int c = cLo; c < cHi; ++c) {
        const float* g = xg + (size_t)c * HW_ + lane * 4;
        #pragma unroll
        for (int t = 0; t < 4; ++t) {
            __builtin_amdgcn_global_load_lds(
                (const __attribute__((address_space(1))) void*)(g + t * 256),
                (__attribute__((address_space(3))) void*)&xs[c * 1024 + t * 256],
                16, 0, 0);
        }
    }
    __syncthreads();   // compiler emits s_waitcnt vmcnt(0) before s_barrier

    const f32x4* xv = (const f32x4*)xs;      // [c][256] float4
    f32x4 mv = xv[tid];
    int i0 = 0, i1 = 0, i2 = 0, i3 = 0;
    #pragma unroll
    for (int c = 1; c < C_; ++c) {
        f32x4 v = xv[c * 256 + tid];
        if (v[0] > mv[0]) { mv[0] = v[0]; i0 = c; }
        if (v[1] > mv[1]) { mv[1] = v[1]; i1 = c; }
        if (v[2] > mv[2]) { mv[2] = v[2]; i2 = c; }
        if (v[3] > mv[3]) { mv[3] = v[3]; i3 = c; }
    }
    const int pix = chunk * 1024 + tid * 4;  // == n*HW_ + p0 + tid*4
    f32x4 s, pf; u8x4 pc;
    s[0] = (mv[0] - ms[i0]) * rs[i0];  pf[0] = (float)i0;  pc[0] = (uint8_t)i0;
    s[1] = (mv[1] - ms[i1]) * rs[i1];  pf[1] = (float)i1;  pc[1] = (uint8_t)i1;
    s[2] = (mv[2] - ms[i2]) * rs[i2];  pf[2] = (float)i2;  pc[2] = (uint8_t)i2;
    s[3] = (mv[3] - ms[i3]) * rs[i3];  pf[3] = (float)i3;  pc[3] = (uint8_t)i3;
    *(f32x4*)(sml + pix) = s;
    *(u8x4*)(pred8 + pix) = pc;
    __builtin_nontemporal_store(pf, (f32x4*)(predf + pix));
}

// ---------------- K2: boundary bits -> packed row masks (8 u64 per row) ------
__global__ __launch_bounds__(256) void k_bnd(
    const uint8_t* __restrict__ pred8, u64* __restrict__ bndM)
{
    int gid  = blockIdx.x * 256 + threadIdx.x;
    int lane = gid & 63;
    int wave = gid >> 6;
    int w = wave & 7;
    int y = (wave >> 3) & 511;
    int n = wave >> 12;
    int xx = w * 64 + lane;
    const uint8_t* pc = pred8 + (size_t)n * HW_ + y * W_ + xx;
    int c = pc[0];
    bool u = y > 0, d = y < H_-1, l = xx > 0, r = xx < W_-1;
    int up = u ? pc[-W_] : c;
    int dn = d ? pc[ W_] : c;
    int lf = l ? pc[-1]  : c;
    int rt = r ? pc[ 1]  : c;
    int mx = max(max(c, up), max(dn, max(lf, rt)));       // cross dilate
    int mn = min(min(c, up), min(dn, min(lf, rt)));       // full 3x3 erode
    int c00 = (u && l) ? pc[-W_-1] : c;
    int c01 = (u && r) ? pc[-W_+1] : c;
    int c10 = (d && l) ? pc[ W_-1] : c;
    int c11 = (d && r) ? pc[ W_+1] : c;
    mn = min(mn, min(min(c00, c01), min(c10, c11)));
    u64 m = __ballot(mx != mn);
    if (lane == 0) bndM[((size_t)n * 512 + y) * 8 + w] = m;
}

// ---------------- K3: fused masks + (skippable) smooth + separable conv ------
__global__ __launch_bounds__(256) void k_fused(
    const float* __restrict__ sml_g, const u64* __restrict__ bndM,
    const float* __restrict__ gk, float* __restrict__ out)
{
    __shared__ float smlA[SR*SC];
    __shared__ float smlB[SR*SC];           // active-staging; later aliased as htmp
    __shared__ u64 M0[BR], E1[BR], E2[BR], E3[BR], VM[BR];
    __shared__ u64 NBM[4][BR];
    __shared__ float g7[7];
    __shared__ int tACT;

    const int tid = threadIdx.x;
    const int bx = blockIdx.x, by = blockIdx.y, n = blockIdx.z;
    const int tx0 = bx * TS, ty0 = by * TS;
    const float* sg = sml_g + (size_t)n * HW_;

    if (tid == 0) tACT = 0;
    if (tid < 7) g7[tid] = gk[21 + tid] / sqrtf(gk[24]);   // kk = outer(g,g)

    // ---- load 52 bnd row-masks (window [tx0-10, tx0+42)) + validity masks ----
    if (tid < BR) {
        int gy = ty0 + tid - 10;
        int bx0 = tx0 - 10;
        u64 m = 0, vm = 0;
        if (gy >= 0 && gy < H_) {
            const u64* row = bndM + ((size_t)n * 512 + gy) * 8;
            int sft = bx0 & 63;
            int wi  = bx0 >> 6;                           // arithmetic: -10 -> -1
            u64 w0 = (wi >= 0) ? row[wi] : 0ULL;
            u64 w1 = (wi + 1 <= 7) ? row[wi + 1] : 0ULL;
            m = sft ? ((w0 >> sft) | (w1 << (64 - sft))) : w0;
            int lo = bx0 < 0 ? -bx0 : 0;
            int hi = (512 - bx0) < BR ? (512 - bx0) : BR;
            if (hi > lo) vm = ((1ULL << (hi - lo)) - 1ULL) << lo;
        }
        M0[tid] = m;
        VM[tid] = vm;
    }

    // ---- load sml region 46x48; OOB -> 0 (zero-pad for conv & masked sums) ----
    if (bx > 0 && bx < (W_/TS - 1)) {
        for (int s = tid; s < SR * (SC/4); s += 256) {
            int ly = s / (SC/4), j = s - ly * (SC/4);
            int gy = ty0 + ly - 7;
            f32x4 v = {0.f, 0.f, 0.f, 0.f};
            if ((unsigned)gy < (unsigned)H_)
                v = *(const f32x4*)(sg + (size_t)gy * W_ + (tx0 - 8) + j * 4);
            *(f32x4*)&smlA[ly * SC + j * 4] = v;
        }
    } else {
        for (int s = tid; s < SR * SC; s += 256) {
            int ly = s / SC, lx = s - ly * SC;
            int gy = ty0 + ly - 7, gx = tx0 + lx - 8;
            float v = 0.f;
            if ((unsigned)gy < (unsigned)H_ && (unsigned)gx < (unsigned)W_)
                v = sg[(size_t)gy * W_ + gx];
            smlA[ly * SC + lx] = v;
        }
    }
    __syncthreads();

    // ---- cross-dilations: E_{k+1}[y] = dx(E_k[y]) | E_k[y-1] | E_k[y+1] ----
    if (tid < BR) {
        u64 a = M0[tid], u = tid > 0 ? M0[tid-1] : 0, d = tid < BR-1 ? M0[tid+1] : 0;
        E1[tid] = a | (a << 1) | (a >> 1) | u | d;
    }
    __syncthreads();
    if (tid < BR) {
        u64 a = E1[tid], u = tid > 0 ? E1[tid-1] : 0, d = tid < BR-1 ? E1[tid+1] : 0;
        E2[tid] = a | (a << 1) | (a >> 1) | u | d;
    }
    __syncthreads();
    if (tid < BR) {
        u64 a = E2[tid], u = tid > 0 ? E2[tid-1] : 0, d = tid < BR-1 ? E2[tid+1] : 0;
        E3[tid] = a | (a << 1) | (a >> 1) | u | d;
    }
    __syncthreads();
    {   // NB_r = ~E_r & valid   (r = 0..3 across the 4 thread quarters)
        int r = tid >> 6, i = tid & 63;
        if (i < BR) {
            u64 e = (r == 0) ? M0[i] : (r == 1) ? E1[i] : (r == 2) ? E2[i] : E3[i];
            NBM[r][i] = ~e & VM[i];
        }
    }
    __syncthreads();

    // ---- active detection: px can change in some pass only if 3x3 window ∩ NB0 ≠ ∅
    u64 actRow = 0;
    if (tid < SR) {
        int bi = tid + 3;
        u64 U = NBM[0][bi-1] | NBM[0][bi] | NBM[0][bi+1];
        u64 A = (U >> 1) | (U >> 2) | (U >> 3);
        int lo = tx0 == 0 ? 8 : 0;
        int hi = tx0 == (W_-TS) ? 40 : SC;
        u64 CV = (hi - lo >= 64) ? ~0ULL : (((1ULL << (hi - lo)) - 1ULL) << lo);
        actRow = A & CV;
        int gy = ty0 + tid - 7;
        if ((unsigned)gy >= (unsigned)H_) actRow = 0;
        if (actRow) tACT = 1;                              // benign race (same value)
    }
    __syncthreads();

    // ---- 4 smoothing passes r=3,2,1,0 — executed only where actives exist ----
    if (tACT) {
        #pragma unroll
        for (int k = 0; k < 4; ++k) {
            const int r = 3 - k;
            const u64 colmask = ((1ULL << (44 - 2*k)) - 1ULL) << (2 + k);
            u64 mwork = 0;
            if (tid >= 1 + k && tid < 45 - k && tid < SR)
                mwork = actRow & colmask;
            u64 mm = mwork;
            while (mm) {
                int lx = __ffsll(mm) - 1; mm &= mm - 1;
                int bi = tid + 3, sh = lx + 1;
                u64 fu = (NBM[r][bi-1] >> sh) & 7ULL;
                u64 fc = (NBM[r][bi  ] >> sh) & 7ULL;
                u64 fd = (NBM[r][bi+1] >> sh) & 7ULL;
                float c = smlA[tid*SC + lx];
                float o;
                if (((fc >> 1) & 1ULL) || !(fu | fc | fd)) {
                    o = c;
                } else {
                    int cnt = __popcll(fu) + __popcll(fc) + __popcll(fd);
                    float sum = 0.f;
                    const float* r0 = &smlA[(tid-1)*SC + lx];
                    const float* r1 = &smlA[(tid  )*SC + lx];
                    const float* r2 = &smlA[(tid+1)*SC + lx];
                    if (fu & 1) sum += r0[-1];
                    if (fu & 2) sum += r0[0];
                    if (fu & 4) sum += r0[1];
                    if (fc & 1) sum += r1[-1];
                    if (fc & 4) sum += r1[1];
                    if (fd & 1) sum += r2[-1];
                    if (fd & 2) sum += r2[0];
                    if (fd & 4) sum += r2[1];
                    o = sum / (float)cnt;
                }
                smlB[tid*SC + lx] = o;
            }
            __syncthreads();
            mm = mwork;
            while (mm) {
                int lx = __ffsll(mm) - 1; mm &= mm - 1;
                smlA[tid*SC + lx] = smlB[tid*SC + lx];
            }
            __syncthreads();
        }
    }

    // ---- separable 7x7 gaussian: horizontal into smlB(htmp), then vertical ----
    float* htmp = smlB;
    for (int s = tid; s < 38 * 32; s += 256) {
        int hy = s >> 5, hx = s & 31;
        const float* p = &smlA[(hy + 4)*SC + (hx + 5)];
        htmp[hy*33 + hx] = g7[0]*p[0] + g7[1]*p[1] + g7[2]*p[2] + g7[3]*p[3]
                         + g7[4]*p[4] + g7[5]*p[5] + g7[6]*p[6];
    }
    __syncthreads();
    for (int s = tid; s < TS*TS; s += 256) {
        int oy = s >> 5, ox = s & 31;
        const float* p = &htmp[oy*33 + ox];
        float a = g7[0]*p[0]   + g7[1]*p[33]  + g7[2]*p[66]  + g7[3]*p[99]
                + g7[4]*p[132] + g7[5]*p[165] + g7[6]*p[198];
        out[(size_t)n*HW_ + (size_t)(ty0 + oy)*W_ + (tx0 + ox)] = a;
    }
}

extern "C" void kernel_launch(void* const* d_in, const int* in_sizes, int n_in,
                              void* d_out, int out_size, void* d_ws, size_t ws_size,
                              hipStream_t stream)
{
    const float* x     = (const float*)d_in[0];
    const float* means = (const float*)d_in[1];
    const float* stdv  = (const float*)d_in[2];
    const float* gk    = (const float*)d_in[3];
    float* out_sml  = (float*)d_out;
    float* out_pred = (float*)d_out + NPIX_;

    char* ws = (char*)d_ws;
    float*   sml   = (float*)(ws);                 // 8,388,608 B
    uint8_t* pred8 = (uint8_t*)(ws + 8388608);     // 2,097,152 B
    u64*     bndM  = (u64*)(ws + 10485760);        //   262,144 B

    k_argmax_sml<<<NPIX_/1024, 256, 0, stream>>>(x, means, stdv, sml, pred8, out_pred);
    k_bnd<<<NPIX_/256, 256, 0, stream>>>(pred8, bndM);
    dim3 fgrd(W_/TS, H_/TS, N_);
    k_fused<<<fgrd, 256, 0, stream>>>(sml, bndM, gk, out_sml);
}

// Round 11
// 51.340 us; speedup vs baseline: 1.7040x; 1.0113x over previous
//
#include <hip/hip_runtime.h>
#include <cstdint>
#include <cstddef>

#define W_ 512
#define H_ 512
#define N_ 8
#define C_ 19
#define HW_ (W_*H_)      // 262144 = 2^18
#define NPIX_ (N_*HW_)   // 2^21

#define TS  32           // output tile side
#define SR  46           // sml region rows (halo 7)
#define SC  48           // sml region cols: [tx0-8, tx0+40)
#define BR  52           // bnd-mask rows per tile: [ty0-10, ty0+42)

typedef float   f32x4 __attribute__((ext_vector_type(4)));
typedef float   f32x2 __attribute__((ext_vector_type(2)));
typedef uint8_t u8x2  __attribute__((ext_vector_type(2)));
typedef unsigned long long u64;

// ---------------- K1: channel max/argmax via global_load_lds DMA staging -----
// R11: 512-px chunks (39 KB LDS -> 4 blocks/CU) for finer DMA/compute
// pipelining across blocks; vmcnt(0) drains half as much per barrier.
__global__ __launch_bounds__(256) void k_argmax_sml(
    const float* __restrict__ x, const float* __restrict__ means,
    const float* __restrict__ stdv, float* __restrict__ sml,
    uint8_t* __restrict__ pred8, float* __restrict__ predf)
{
    __shared__ float xs[C_ * 512];       // [c][512 px]  38,912 B
    __shared__ float ms[C_], rs[C_];
    const int tid = threadIdx.x;
    if (tid < C_) {
        ms[tid] = means[tid];
        rs[tid] = __builtin_amdgcn_rcpf(stdv[tid]);
    }

    const int chunk = blockIdx.x;            // 512 px per block, 4096 blocks
    const int n   = chunk >> 9;              // 512 chunks/image
    const int p0  = (chunk & 511) << 9;
    const int wv  = tid >> 6, lane = tid & 63;
    const float* xg = x + (size_t)n * C_ * HW_ + p0;

    // wave wv stages channels [5*wv, 5*wv+5) (wave 3: 4 ch); 2 x 1KB DMA each
    int cLo = wv * 5;
    int cHi = cLo + 5 > C_ ? C_ : cLo + 5;
    for (int c = cLo; c < cHi; ++c) {
        const float* g = xg + (size_t)c * HW_ + lane * 4;
        #pragma unroll
        for (int t = 0; t < 2; ++t) {
            __builtin_amdgcn_global_load_lds(
                (const __attribute__((address_space(1))) void*)(g + t * 256),
                (__attribute__((address_space(3))) void*)&xs[c * 512 + t * 256],
                16, 0, 0);
        }
    }
    __syncthreads();   // vmcnt(0) drain + barrier

    const f32x2* xv = (const f32x2*)xs;      // [c][256] float2
    f32x2 mv = xv[tid];
    int i0 = 0, i1 = 0;
    #pragma unroll
    for (int c = 1; c < C_; ++c) {
        f32x2 v = xv[c * 256 + tid];
        if (v[0] > mv[0]) { mv[0] = v[0]; i0 = c; }
        if (v[1] > mv[1]) { mv[1] = v[1]; i1 = c; }
    }
    const int pix = chunk * 512 + tid * 2;
    f32x2 s, pf; u8x2 pc;
    s[0] = (mv[0] - ms[i0]) * rs[i0];  pf[0] = (float)i0;  pc[0] = (uint8_t)i0;
    s[1] = (mv[1] - ms[i1]) * rs[i1];  pf[1] = (float)i1;  pc[1] = (uint8_t)i1;
    *(f32x2*)(sml + pix) = s;
    *(u8x2*)(pred8 + pix) = pc;
    __builtin_nontemporal_store(pf, (f32x2*)(predf + pix));
}

// ---------------- K2: boundary bits -> packed row masks (8 u64 per row) ------
__global__ __launch_bounds__(256) void k_bnd(
    const uint8_t* __restrict__ pred8, u64* __restrict__ bndM)
{
    int gid  = blockIdx.x * 256 + threadIdx.x;
    int lane = gid & 63;
    int wave = gid >> 6;
    int w = wave & 7;
    int y = (wave >> 3) & 511;
    int n = wave >> 12;
    int xx = w * 64 + lane;
    const uint8_t* pc = pred8 + (size_t)n * HW_ + y * W_ + xx;
    int c = pc[0];
    bool u = y > 0, d = y < H_-1, l = xx > 0, r = xx < W_-1;
    int up = u ? pc[-W_] : c;
    int dn = d ? pc[ W_] : c;
    int lf = l ? pc[-1]  : c;
    int rt = r ? pc[ 1]  : c;
    int mx = max(max(c, up), max(dn, max(lf, rt)));       // cross dilate
    int mn = min(min(c, up), min(dn, min(lf, rt)));       // full 3x3 erode
    int c00 = (u && l) ? pc[-W_-1] : c;
    int c01 = (u && r) ? pc[-W_+1] : c;
    int c10 = (d && l) ? pc[ W_-1] : c;
    int c11 = (d && r) ? pc[ W_+1] : c;
    mn = min(mn, min(min(c00, c01), min(c10, c11)));
    u64 m = __ballot(mx != mn);
    if (lane == 0) bndM[((size_t)n * 512 + y) * 8 + w] = m;
}

// ---------------- K3: fused masks + hot/cold paths + separable conv ----------
// Hot (tACT==0, ~all tiles on this input): no pixel within halo-3 of the
// output tile can change in any smoothing pass -> load only the 38x40 conv
// support, skip dilations/smooth. Cold: full R10 machinery.
__global__ __launch_bounds__(256) void k_fused(
    const float* __restrict__ sml_g, const u64* __restrict__ bndM,
    const float* __restrict__ gk, float* __restrict__ out)
{
    __shared__ float smlA[SR*SC];
    __shared__ float smlB[SR*SC];           // staging; aliased as htmp
    __shared__ u64 M0[BR], E1[BR], E2[BR], E3[BR], VM[BR];
    __shared__ u64 NBM[4][BR];
    __shared__ float g7[7];
    __shared__ int tACT;

    const int tid = threadIdx.x;
    const int bx = blockIdx.x, by = blockIdx.y, n = blockIdx.z;
    const int tx0 = bx * TS, ty0 = by * TS;
    const float* sg = sml_g + (size_t)n * HW_;

    if (tid == 0) tACT = 0;
    if (tid < 7) g7[tid] = gk[21 + tid] / sqrtf(gk[24]);   // kk = outer(g,g)

    // ---- load 52 bnd row-masks (window [tx0-10, tx0+42)) + validity masks ----
    if (tid < BR) {
        int gy = ty0 + tid - 10;
        int bx0 = tx0 - 10;
        u64 m = 0, vm = 0;
        if (gy >= 0 && gy < H_) {
            const u64* row = bndM + ((size_t)n * 512 + gy) * 8;
            int sft = bx0 & 63;
            int wi  = bx0 >> 6;                           // arithmetic: -10 -> -1
            u64 w0 = (wi >= 0) ? row[wi] : 0ULL;
            u64 w1 = (wi + 1 <= 7) ? row[wi + 1] : 0ULL;
            m = sft ? ((w0 >> sft) | (w1 << (64 - sft))) : w0;
            int lo = bx0 < 0 ? -bx0 : 0;
            int hi = (512 - bx0) < BR ? (512 - bx0) : BR;
            if (hi > lo) vm = ((1ULL << (hi - lo)) - 1ULL) << lo;
        }
        M0[tid] = m;
        VM[tid] = vm;
    }
    __syncthreads();

    // ---- active detection from NB0 = ~M0 & VM (no dilations needed) ----
    u64 actRow = 0;
    if (tid < SR) {
        int bi = tid + 3;                                  // mask row for sml row tid
        u64 nbU = ~M0[bi-1] & VM[bi-1];
        u64 nbC = ~M0[bi  ] & VM[bi  ];
        u64 nbD = ~M0[bi+1] & VM[bi+1];
        u64 U = nbU | nbC | nbD;
        u64 A = (U >> 1) | (U >> 2) | (U >> 3);            // bit lx <- bits lx+1..lx+3
        int lo = tx0 == 0 ? 8 : 0;
        int hi = tx0 == (W_-TS) ? 40 : SC;
        u64 CV = (hi - lo >= 64) ? ~0ULL : (((1ULL << (hi - lo)) - 1ULL) << lo);
        actRow = A & CV;
        int gy = ty0 + tid - 7;
        if ((unsigned)gy >= (unsigned)H_) actRow = 0;
        if (actRow) tACT = 1;                              // benign race (same value)
    }
    __syncthreads();

    if (!tACT) {
        // ======== HOT PATH: conv only; load rows [4,42) x cols [4,44) ========
        for (int s = tid; s < 38 * 10; s += 256) {
            int q  = s / 10;
            int ly = 4 + q, lx4 = s - q * 10;
            int gy = ty0 + ly - 7;                         // [ty0-3, ty0+35)
            int gx = tx0 - 4 + lx4 * 4;                    // [tx0-4, tx0+36), 16B-aligned
            f32x4 v = {0.f, 0.f, 0.f, 0.f};
            if ((unsigned)gy < (unsigned)H_ && (unsigned)gx < (unsigned)W_)
                v = *(const f32x4*)(sg + (size_t)gy * W_ + gx);
            *(f32x4*)&smlA[ly * SC + 4 + lx4 * 4] = v;     // OOB float4s are fully OOB
        }
        __syncthreads();
        float* htmp = smlB;
        for (int s = tid; s < 38 * 32; s += 256) {
            int hy = s >> 5, hx = s & 31;
            const float* p = &smlA[(hy + 4)*SC + (hx + 5)];
            htmp[hy*33 + hx] = g7[0]*p[0] + g7[1]*p[1] + g7[2]*p[2] + g7[3]*p[3]
                             + g7[4]*p[4] + g7[5]*p[5] + g7[6]*p[6];
        }
        __syncthreads();
        for (int s = tid; s < TS*TS; s += 256) {
            int oy = s >> 5, ox = s & 31;
            const float* p = &htmp[oy*33 + ox];
            float a = g7[0]*p[0]   + g7[1]*p[33]  + g7[2]*p[66]  + g7[3]*p[99]
                    + g7[4]*p[132] + g7[5]*p[165] + g7[6]*p[198];
            out[(size_t)n*HW_ + (size_t)(ty0 + oy)*W_ + (tx0 + ox)] = a;
        }
        return;
    }

    // ======== COLD PATH: full R10 machinery ========
    // ---- load sml region 46x48; OOB -> 0 ----
    if (bx > 0 && bx < (W_/TS - 1)) {
        for (int s = tid; s < SR * (SC/4); s += 256) {
            int ly = s / (SC/4), j = s - ly * (SC/4);
            int gy = ty0 + ly - 7;
            f32x4 v = {0.f, 0.f, 0.f, 0.f};
            if ((unsigned)gy < (unsigned)H_)
                v = *(const f32x4*)(sg + (size_t)gy * W_ + (tx0 - 8) + j * 4);
            *(f32x4*)&smlA[ly * SC + j * 4] = v;
        }
    } else {
        for (int s = tid; s < SR * SC; s += 256) {
            int ly = s / SC, lx = s - ly * SC;
            int gy = ty0 + ly - 7, gx = tx0 + lx - 8;
            float v = 0.f;
            if ((unsigned)gy < (unsigned)H_ && (unsigned)gx < (unsigned)W_)
                v = sg[(size_t)gy * W_ + gx];
            smlA[ly * SC + lx] = v;
        }
    }
    __syncthreads();

    // ---- cross-dilations ----
    if (tid < BR) {
        u64 a = M0[tid], u = tid > 0 ? M0[tid-1] : 0, d = tid < BR-1 ? M0[tid+1] : 0;
        E1[tid] = a | (a << 1) | (a >> 1) | u | d;
    }
    __syncthreads();
    if (tid < BR) {
        u64 a = E1[tid], u = tid > 0 ? E1[tid-1] : 0, d = tid < BR-1 ? E1[tid+1] : 0;
        E2[tid] = a | (a << 1) | (a >> 1) | u | d;
    }
    __syncthreads();
    if (tid < BR) {
        u64 a = E2[tid], u = tid > 0 ? E2[tid-1] : 0, d = tid < BR-1 ? E2[tid+1] : 0;
        E3[tid] = a | (a << 1) | (a >> 1) | u | d;
    }
    __syncthreads();
    {   // NB_r = ~E_r & valid
        int r = tid >> 6, i = tid & 63;
        if (i < BR) {
            u64 e = (r == 0) ? M0[i] : (r == 1) ? E1[i] : (r == 2) ? E2[i] : E3[i];
            NBM[r][i] = ~e & VM[i];
        }
    }
    __syncthreads();

    // ---- 4 smoothing passes r=3,2,1,0 on active pixels ----
    #pragma unroll
    for (int k = 0; k < 4; ++k) {
        const int r = 3 - k;
        const u64 colmask = ((1ULL << (44 - 2*k)) - 1ULL) << (2 + k);
        u64 mwork = 0;
        if (tid >= 1 + k && tid < 45 - k && tid < SR)
            mwork = actRow & colmask;
        u64 mm = mwork;
        while (mm) {
            int lx = __ffsll(mm) - 1; mm &= mm - 1;
            int bi = tid + 3, sh = lx + 1;
            u64 fu = (NBM[r][bi-1] >> sh) & 7ULL;
            u64 fc = (NBM[r][bi  ] >> sh) & 7ULL;
            u64 fd = (NBM[r][bi+1] >> sh) & 7ULL;
            float c = smlA[tid*SC + lx];
            float o;
            if (((fc >> 1) & 1ULL) || !(fu | fc | fd)) {
                o = c;
            } else {
                int cnt = __popcll(fu) + __popcll(fc) + __popcll(fd);
                float sum = 0.f;
                const float* r0 = &smlA[(tid-1)*SC + lx];
                const float* r1 = &smlA[(tid  )*SC + lx];
                const float* r2 = &smlA[(tid+1)*SC + lx];
                if (fu & 1) sum += r0[-1];
                if (fu & 2) sum += r0[0];
                if (fu & 4) sum += r0[1];
                if (fc & 1) sum += r1[-1];
                if (fc & 4) sum += r1[1];
                if (fd & 1) sum += r2[-1];
                if (fd & 2) sum += r2[0];
                if (fd & 4) sum += r2[1];
                o = sum / (float)cnt;
            }
            smlB[tid*SC + lx] = o;
        }
        __syncthreads();
        mm = mwork;
        while (mm) {
            int lx = __ffsll(mm) - 1; mm &= mm - 1;
            smlA[tid*SC + lx] = smlB[tid*SC + lx];
        }
        __syncthreads();
    }

    // ---- separable conv ----
    float* htmp = smlB;
    for (int s = tid; s < 38 * 32; s += 256) {
        int hy = s >> 5, hx = s & 31;
        const float* p = &smlA[(hy + 4)*SC + (hx + 5)];
        htmp[hy*33 + hx] = g7[0]*p[0] + g7[1]*p[1] + g7[2]*p[2] + g7[3]*p[3]
                         + g7[4]*p[4] + g7[5]*p[5] + g7[6]*p[6];
    }
    __syncthreads();
    for (int s = tid; s < TS*TS; s += 256) {
        int oy = s >> 5, ox = s & 31;
        const float* p = &htmp[oy*33 + ox];
        float a = g7[0]*p[0]   + g7[1]*p[33]  + g7[2]*p[66]  + g7[3]*p[99]
                + g7[4]*p[132] + g7[5]*p[165] + g7[6]*p[198];
        out[(size_t)n*HW_ + (size_t)(ty0 + oy)*W_ + (tx0 + ox)] = a;
    }
}

extern "C" void kernel_launch(void* const* d_in, const int* in_sizes, int n_in,
                              void* d_out, int out_size, void* d_ws, size_t ws_size,
                              hipStream_t stream)
{
    const float* x     = (const float*)d_in[0];
    const float* means = (const float*)d_in[1];
    const float* stdv  = (const float*)d_in[2];
    const float* gk    = (const float*)d_in[3];
    float* out_sml  = (float*)d_out;
    float* out_pred = (float*)d_out + NPIX_;

    char* ws = (char*)d_ws;
    float*   sml   = (float*)(ws);                 // 8,388,608 B
    uint8_t* pred8 = (uint8_t*)(ws + 8388608);     // 2,097,152 B
    u64*     bndM  = (u64*)(ws + 10485760);        //   262,144 B

    k_argmax_sml<<<NPIX_/512, 256, 0, stream>>>(x, means, stdv, sml, pred8, out_pred);
    k_bnd<<<NPIX_/256, 256, 0, stream>>>(pred8, bndM);
    dim3 fgrd(W_/TS, H_/TS, N_);
    k_fused<<<fgrd, 256, 0, stream>>>(sml, bndM, gk, out_sml);
}